// Round 1
// baseline (566.591 us; speedup 1.0000x reference)
//
#include <hip/hip_runtime.h>

#define BB 16
#define NN 2048
#define DD 64
#define MC 128
#define NCH (NN / MC)
#define TM 8

typedef __bf16 bf16x8 __attribute__((ext_vector_type(8)));
typedef float f32x4 __attribute__((ext_vector_type(4)));
typedef int i32x4 __attribute__((ext_vector_type(4)));

#define MFMA16 __builtin_amdgcn_mfma_f32_16x16x32_bf16

__device__ inline unsigned short f2bf(float f) {
  unsigned u = __float_as_uint(f);
  unsigned r = u + 0x7FFFu + ((u >> 16) & 1u);
  return (unsigned short)(r >> 16);
}
__device__ inline float bf2f(unsigned short h) {
  return __uint_as_float(((unsigned)h) << 16);
}
__device__ inline bf16x8 ldfrag(const unsigned short* p) {
  i32x4 v = *reinterpret_cast<const i32x4*>(p);
  return __builtin_bit_cast(bf16x8, v);
}

// one 16x16 output tile of split-bf16 x@x^T (hh + hl + lh terms)
__device__ inline f32x4 dyn_tile(const unsigned short* __restrict__ hi,
                                 const unsigned short* __restrict__ lo,
                                 size_t bidx, bf16x8 ah0, bf16x8 ah1,
                                 bf16x8 al0, bf16x8 al1) {
  bf16x8 bh0 = ldfrag(hi + bidx), bh1 = ldfrag(hi + bidx + 32);
  bf16x8 bl0 = ldfrag(lo + bidx), bl1 = ldfrag(lo + bidx + 32);
  f32x4 a = {0.f, 0.f, 0.f, 0.f};
  a = MFMA16(ah0, bh0, a, 0, 0, 0);
  a = MFMA16(ah1, bh1, a, 0, 0, 0);
  a = MFMA16(ah0, bl0, a, 0, 0, 0);
  a = MFMA16(ah1, bl1, a, 0, 0, 0);
  a = MFMA16(al0, bh0, a, 0, 0, 0);
  a = MFMA16(al1, bh1, a, 0, 0, 0);
  return a;
}

// ---------------------------------------------------------------------------
// prep: node1/node2 fp32 (for fallback) + bf16 hi/lo splits (for MFMA path)
// ---------------------------------------------------------------------------
__global__ __launch_bounds__(256) void prep_nodes(
    const float* __restrict__ emb, const float* __restrict__ w1w,
    const float* __restrict__ w1b, const float* __restrict__ w2w,
    const float* __restrict__ w2b, float* __restrict__ n1f,
    float* __restrict__ n2f, unsigned short* __restrict__ n1hi,
    unsigned short* __restrict__ n1lo, unsigned short* __restrict__ n2hi,
    unsigned short* __restrict__ n2lo, int wantbf)
{
  __shared__ float wl[2][DD][DD];
  int t = threadIdx.x;
  for (int i = t; i < DD * DD; i += 256) {
    wl[0][i >> 6][i & 63] = w1w[i];
    wl[1][i >> 6][i & 63] = w2w[i];
  }
  __syncthreads();
  int g = blockIdx.x * 256 + t;
  int which = (g >= NN * DD) ? 1 : 0;
  int idx = which ? g - NN * DD : g;
  int n = idx >> 6, d = idx & 63;
  const float* e = emb + (size_t)n * DD;
  float s = which ? w2b[d] : w1b[d];
  #pragma unroll
  for (int k = 0; k < DD; ++k) s += e[k] * wl[which][d][k];
  (which ? n2f : n1f)[idx] = s;
  if (wantbf) {
    unsigned short hi = f2bf(s);
    unsigned short lo = f2bf(s - bf2f(hi));
    (which ? n2hi : n1hi)[idx] = hi;
    (which ? n2lo : n1lo)[idx] = lo;
  }
}

// ---------------------------------------------------------------------------
// prep: x -> bf16 hi/lo split arrays, fused with v[b,n] = x[b,n,:].wp + wp_b
// (16 consecutive threads cover one row of 64 elems; shuffle-reduce the dot)
// ---------------------------------------------------------------------------
__global__ __launch_bounds__(256) void prep_x(
    const float* __restrict__ x, const float* __restrict__ wpw,
    const float* __restrict__ wpb, unsigned short* __restrict__ xhi,
    unsigned short* __restrict__ xlo, float* __restrict__ v)
{
  int t = threadIdx.x;
  int g = blockIdx.x * 256 + t;
  int e0 = g * 4;
  float4 xx = *(const float4*)&x[e0];
  ushort4 hi, lo;
  hi.x = f2bf(xx.x); lo.x = f2bf(xx.x - bf2f(hi.x));
  hi.y = f2bf(xx.y); lo.y = f2bf(xx.y - bf2f(hi.y));
  hi.z = f2bf(xx.z); lo.z = f2bf(xx.z - bf2f(hi.z));
  hi.w = f2bf(xx.w); lo.w = f2bf(xx.w - bf2f(hi.w));
  *(ushort4*)&xhi[e0] = hi;
  *(ushort4*)&xlo[e0] = lo;
  float4 wq = *(const float4*)&wpw[(t & 15) * 4];
  float s = xx.x * wq.x + xx.y * wq.y + xx.z * wq.z + xx.w * wq.w;
  s += __shfl_xor(s, 1, 64);
  s += __shfl_xor(s, 2, 64);
  s += __shfl_xor(s, 4, 64);
  s += __shfl_xor(s, 8, 64);
  if ((t & 15) == 0) v[g >> 4] = s + wpb[0];
}

// ---------------------------------------------------------------------------
// prep_v kept for the small-ws fallback path only
// ---------------------------------------------------------------------------
__global__ __launch_bounds__(256) void prep_v(
    const float* __restrict__ x, const float* __restrict__ wpw,
    const float* __restrict__ wpb, float* __restrict__ v)
{
  int g = blockIdx.x * 256 + threadIdx.x;
  const float* xr = x + (size_t)g * DD;
  float s = wpb[0];
  #pragma unroll
  for (int kq = 0; kq < DD / 4; ++kq) {
    float4 q = *(const float4*)&xr[kq * 4];
    float4 w = *(const float4*)&wpw[kq * 4];
    s += q.x * w.x + q.y * w.y + q.z * w.z + q.w * w.w;
  }
  v[g] = s;
}

// ---------------------------------------------------------------------------
// base = relu(n1 @ n2^T) via split-bf16 MFMA.
// grid (128 row-blocks, 8 col-chunks): 1024 blocks, wave owns 16 rows x 64 cols
// (old version was 128 blocks = 2 waves/CU -> pure latency exposure)
// ---------------------------------------------------------------------------
__global__ __launch_bounds__(256) void base_mfma(
    const unsigned short* __restrict__ n1hi, const unsigned short* __restrict__ n1lo,
    const unsigned short* __restrict__ n2hi, const unsigned short* __restrict__ n2lo,
    float* __restrict__ base)
{
  int t = threadIdx.x, lane = t & 63, w = t >> 6;
  int q = lane >> 4, m = lane & 15;
  int n0 = blockIdx.x * 16;
  int cw = blockIdx.y * 256 + w * 64;
  int aidx = (n0 + m) * DD + q * 8;
  bf16x8 ah0 = ldfrag(n1hi + aidx), ah1 = ldfrag(n1hi + aidx + 32);
  bf16x8 al0 = ldfrag(n1lo + aidx), al1 = ldfrag(n1lo + aidx + 32);
  #pragma unroll
  for (int tt = 0; tt < 4; ++tt) {
    int c = cw + tt * 16 + m;
    f32x4 acc = dyn_tile(n2hi, n2lo, (size_t)c * DD + q * 8, ah0, ah1, al0, al1);
    #pragma unroll
    for (int r = 0; r < 4; ++r)
      base[(size_t)(n0 + q * 4 + r) * NN + c] = fmaxf(acc[r], 0.f);
  }
}

// ---------------------------------------------------------------------------
// fused: two-pass flash-style softmax. Never materializes the 2048-wide row.
// Pass 1: MFMA tiles + online (m,s). Reduce across lanes/waves.
// Pass 2: recompute tiles (bitwise-identical) and write exp(a-M)*invS.
// Register footprint ~75 instead of ~230 -> 4x the resident waves.
// grid (128 row-blocks, 16 batches), 256 thr. Wave owns 16 rows x 512 cols.
// C/D layout: col = lane&15, row = (lane>>4)*4 + reg.
// ---------------------------------------------------------------------------
__global__ __launch_bounds__(256, 4) void fused_mfma(
    const unsigned short* __restrict__ xhi, const unsigned short* __restrict__ xlo,
    const float* __restrict__ base, const float* __restrict__ vv,
    float* __restrict__ out)
{
  __shared__ float redm[4][16];
  __shared__ float reds[4][16];
  int t = threadIdx.x, lane = t & 63, w = t >> 6;
  int q = lane >> 4, m = lane & 15;
  int b = blockIdx.y, n0 = blockIdx.x * 16, cw = w * 512;
  size_t xb = (size_t)b * NN * DD;

  int aoff = (n0 + m) * DD + q * 8;
  bf16x8 ah0 = ldfrag(xhi + xb + aoff), ah1 = ldfrag(xhi + xb + aoff + 32);
  bf16x8 al0 = ldfrag(xlo + xb + aoff), al1 = ldfrag(xlo + xb + aoff + 32);

  float vrow[4];
  #pragma unroll
  for (int r = 0; r < 4; ++r) vrow[r] = vv[b * NN + n0 + q * 4 + r];

  // -------- pass 1: online (m, s) over this lane's 32 columns --------
  float mrun[4], srun[4];
  #pragma unroll
  for (int r = 0; r < 4; ++r) { mrun[r] = -INFINITY; srun[r] = 0.f; }

  #pragma unroll
  for (int tt = 0; tt < 32; ++tt) {
    int c = cw + tt * 16 + m;
    f32x4 a = dyn_tile(xhi, xlo, xb + (size_t)c * DD + q * 8, ah0, ah1, al0, al1);
    float vc = vv[b * NN + c];
    #pragma unroll
    for (int r = 0; r < 4; ++r) {
      float av = a[r] + base[(size_t)(n0 + q * 4 + r) * NN + c] + vrow[r] - vc;
      float nm = fmaxf(mrun[r], av);
      srun[r] = srun[r] * __expf(mrun[r] - nm) + __expf(av - nm);
      mrun[r] = nm;
    }
  }

  // reduce across the 16 column-lanes of each quad-row group
  #pragma unroll
  for (int off = 8; off >= 1; off >>= 1) {
    #pragma unroll
    for (int r = 0; r < 4; ++r) {
      float om = __shfl_xor(mrun[r], off, 64);
      float os = __shfl_xor(srun[r], off, 64);
      float nm = fmaxf(mrun[r], om);
      srun[r] = srun[r] * __expf(mrun[r] - nm) + os * __expf(om - nm);
      mrun[r] = nm;
    }
  }
  if (m == 0) {
    #pragma unroll
    for (int r = 0; r < 4; ++r) {
      redm[w][q * 4 + r] = mrun[r];
      reds[w][q * 4 + r] = srun[r];
    }
  }
  __syncthreads();

  float M[4], inv[4];
  #pragma unroll
  for (int r = 0; r < 4; ++r) {
    int rr = q * 4 + r;
    float m0 = redm[0][rr], m1 = redm[1][rr], m2 = redm[2][rr], m3 = redm[3][rr];
    float Mr = fmaxf(fmaxf(m0, m1), fmaxf(m2, m3));
    float S = reds[0][rr] * __expf(m0 - Mr) + reds[1][rr] * __expf(m1 - Mr)
            + reds[2][rr] * __expf(m2 - Mr) + reds[3][rr] * __expf(m3 - Mr);
    M[r] = Mr;
    inv[r] = 1.f / S;
  }

  // -------- pass 2: recompute (deterministic) and stream out --------
  #pragma unroll
  for (int tt = 0; tt < 32; ++tt) {
    int c = cw + tt * 16 + m;
    f32x4 a = dyn_tile(xhi, xlo, xb + (size_t)c * DD + q * 8, ah0, ah1, al0, al1);
    float vc = vv[b * NN + c];
    #pragma unroll
    for (int r = 0; r < 4; ++r) {
      float av = a[r] + base[(size_t)(n0 + q * 4 + r) * NN + c] + vrow[r] - vc;
      float o = __expf(av - M[r]) * inv[r];
      __builtin_nontemporal_store(o, &out[((size_t)b * NN + n0 + q * 4 + r) * NN + c]);
    }
  }
}

// ---------------------------------------------------------------------------
// small-ws fallback (R1 VALU path, recomputes base dot per block)
// ---------------------------------------------------------------------------
__global__ __launch_bounds__(256) void fused_fallback(
    const float* __restrict__ x, const float* __restrict__ node1,
    const float* __restrict__ node2, const float* __restrict__ vv,
    float* __restrict__ out)
{
  __shared__ float xr[TM][DD];
  __shared__ float n1r[TM][DD];
  __shared__ float colbuf[2][DD / 2][MC + 1];
  __shared__ float redm[4][4];
  __shared__ float reds[4][4];

  int t = threadIdx.x;
  int b = blockIdx.y;
  int n0 = blockIdx.x * TM;
  int mloc = t & (MC - 1);
  int grp = t >> 7;
  int r0 = grp * 4;

  for (int i = t; i < TM * DD; i += 256) {
    xr[i >> 6][i & 63] = x[((size_t)b * NN + n0) * DD + i];
    n1r[i >> 6][i & 63] = node1[(size_t)n0 * DD + i];
  }
  float vrow[4];
  #pragma unroll
  for (int r = 0; r < 4; ++r) vrow[r] = vv[b * NN + n0 + r0 + r];

  float acc[4][NCH];

  #pragma unroll
  for (int c = 0; c < NCH; ++c) {
    float dacc[4] = {0.f, 0.f, 0.f, 0.f};
    float bacc[4] = {0.f, 0.f, 0.f, 0.f};
    #pragma unroll
    for (int h = 0; h < 2; ++h) {
      __syncthreads();
      #pragma unroll
      for (int i = 0; i < 8; ++i) {
        int f = i * 256 + t;
        int arr = f >> 10;
        int ff = f & 1023;
        int mm = ff >> 3, kq = ff & 7;
        const float* src = arr
            ? node2 + (size_t)(c * MC + mm) * DD + h * 32 + kq * 4
            : x + ((size_t)b * NN + c * MC + mm) * DD + h * 32 + kq * 4;
        float4 qv = *(const float4*)src;
        colbuf[arr][kq * 4 + 0][mm] = qv.x;
        colbuf[arr][kq * 4 + 1][mm] = qv.y;
        colbuf[arr][kq * 4 + 2][mm] = qv.z;
        colbuf[arr][kq * 4 + 3][mm] = qv.w;
      }
      __syncthreads();
      #pragma unroll
      for (int kb = 0; kb < 8; ++kb) {
        float ra[4][4], rb[4][4];
        #pragma unroll
        for (int r = 0; r < 4; ++r) {
          float4 qx = *(const float4*)&xr[r0 + r][h * 32 + kb * 4];
          ra[r][0] = qx.x; ra[r][1] = qx.y; ra[r][2] = qx.z; ra[r][3] = qx.w;
          float4 qn = *(const float4*)&n1r[r0 + r][h * 32 + kb * 4];
          rb[r][0] = qn.x; rb[r][1] = qn.y; rb[r][2] = qn.z; rb[r][3] = qn.w;
        }
        #pragma unroll
        for (int kk = 0; kk < 4; ++kk) {
          float cx = colbuf[0][kb * 4 + kk][mloc];
          float cn = colbuf[1][kb * 4 + kk][mloc];
          #pragma unroll
          for (int r = 0; r < 4; ++r) {
            dacc[r] += ra[r][kk] * cx;
            bacc[r] += rb[r][kk] * cn;
          }
        }
      }
    }
    float vc = vv[b * NN + c * MC + mloc];
    #pragma unroll
    for (int r = 0; r < 4; ++r)
      acc[r][c] = dacc[r] + vrow[r] - vc + fmaxf(bacc[r], 0.f);
  }

  float pm[4];
  #pragma unroll
  for (int r = 0; r < 4; ++r) {
    float mv = acc[r][0];
    #pragma unroll
    for (int c = 1; c < NCH; ++c) mv = fmaxf(mv, acc[r][c]);
    #pragma unroll
    for (int off = 32; off >= 1; off >>= 1)
      mv = fmaxf(mv, __shfl_xor(mv, off, 64));
    pm[r] = mv;
  }
  int w = t >> 6;
  if ((t & 63) == 0) {
    #pragma unroll
    for (int r = 0; r < 4; ++r) redm[w][r] = pm[r];
  }
  __syncthreads();
  float mrow[4], ps[4];
  #pragma unroll
  for (int r = 0; r < 4; ++r) {
    mrow[r] = fmaxf(redm[grp * 2][r], redm[grp * 2 + 1][r]);
    ps[r] = 0.f;
  }
  #pragma unroll
  for (int c = 0; c < NCH; ++c)
    #pragma unroll
    for (int r = 0; r < 4; ++r) {
      float e = __expf(acc[r][c] - mrow[r]);
      acc[r][c] = e;
      ps[r] += e;
    }
  #pragma unroll
  for (int r = 0; r < 4; ++r)
    #pragma unroll
    for (int off = 32; off >= 1; off >>= 1)
      ps[r] += __shfl_xor(ps[r], off, 64);
  if ((t & 63) == 0) {
    #pragma unroll
    for (int r = 0; r < 4; ++r) reds[w][r] = ps[r];
  }
  __syncthreads();
  float inv[4];
  #pragma unroll
  for (int r = 0; r < 4; ++r)
    inv[r] = 1.f / (reds[grp * 2][r] + reds[grp * 2 + 1][r]);
  #pragma unroll
  for (int c = 0; c < NCH; ++c)
    #pragma unroll
    for (int r = 0; r < 4; ++r)
      out[((size_t)b * NN + n0 + r0 + r) * NN + c * MC + mloc] = acc[r][c] * inv[r];
}

// ---------------------------------------------------------------------------
extern "C" void kernel_launch(void* const* d_in, const int* in_sizes, int n_in,
                              void* d_out, int out_size, void* d_ws, size_t ws_size,
                              hipStream_t stream)
{
  const float* x   = (const float*)d_in[0];
  const float* emb = (const float*)d_in[1];
  const float* w1w = (const float*)d_in[2];
  const float* w1b = (const float*)d_in[3];
  const float* w2w = (const float*)d_in[4];
  const float* w2b = (const float*)d_in[5];
  const float* wpw = (const float*)d_in[6];
  const float* wpb = (const float*)d_in[7];
  float* out = (float*)d_out;

  float* wsf   = (float*)d_ws;
  float* node1 = wsf;
  float* node2 = wsf + (size_t)NN * DD;
  float* v     = wsf + (size_t)2 * NN * DD;
  float* base  = wsf + (size_t)2 * NN * DD + (size_t)BB * NN;
  unsigned short* bfb = (unsigned short*)(base + (size_t)NN * NN);
  unsigned short* xhi = bfb;
  unsigned short* xlo = xhi + (size_t)BB * NN * DD;
  unsigned short* n1hi = xlo + (size_t)BB * NN * DD;
  unsigned short* n1lo = n1hi + (size_t)NN * DD;
  unsigned short* n2hi = n1lo + (size_t)NN * DD;
  unsigned short* n2lo = n2hi + (size_t)NN * DD;

  size_t need_mfma = ((size_t)2 * NN * DD + (size_t)BB * NN + (size_t)NN * NN) * 4
                   + ((size_t)2 * BB * NN * DD + (size_t)4 * NN * DD) * 2;
  bool big = ws_size >= need_mfma;

  prep_nodes<<<2 * NN * DD / 256, 256, 0, stream>>>(
      emb, w1w, w1b, w2w, w2b, node1, node2, n1hi, n1lo, n2hi, n2lo, big ? 1 : 0);

  if (big) {
    prep_x<<<BB * NN * DD / 4 / 256, 256, 0, stream>>>(x, wpw, wpb, xhi, xlo, v);
    dim3 bgrid(NN / 16, 8);
    base_mfma<<<bgrid, 256, 0, stream>>>(n1hi, n1lo, n2hi, n2lo, base);
    dim3 grid(NN / 16, BB);
    fused_mfma<<<grid, 256, 0, stream>>>(xhi, xlo, base, v, out);
  } else {
    prep_v<<<BB * NN / 256, 256, 0, stream>>>(x, wpw, wpb, v);
    dim3 grid(NN / TM, BB);
    fused_fallback<<<grid, 256, 0, stream>>>(x, node1, node2, v, out);
  }
}

// Round 2
// 447.019 us; speedup vs baseline: 1.2675x; 1.2675x over previous
//
#include <hip/hip_runtime.h>

#define BB 16
#define NN 2048
#define DD 64
#define MC 128
#define NCH (NN / MC)
#define TM 8

// fused_mfma geometry: 512 threads = 8 waves, wave owns 16 rows x 256 cols
#define FW 8          // waves per block
#define FT 16         // 16x16 tiles per wave (256 cols)

typedef __bf16 bf16x8 __attribute__((ext_vector_type(8)));
typedef float f32x4 __attribute__((ext_vector_type(4)));
typedef int i32x4 __attribute__((ext_vector_type(4)));

#define MFMA16 __builtin_amdgcn_mfma_f32_16x16x32_bf16

__device__ inline unsigned short f2bf(float f) {
  unsigned u = __float_as_uint(f);
  unsigned r = u + 0x7FFFu + ((u >> 16) & 1u);
  return (unsigned short)(r >> 16);
}
__device__ inline float bf2f(unsigned short h) {
  return __uint_as_float(((unsigned)h) << 16);
}
__device__ inline bf16x8 ldfrag(const unsigned short* p) {
  i32x4 v = *reinterpret_cast<const i32x4*>(p);
  return __builtin_bit_cast(bf16x8, v);
}

// ---------------------------------------------------------------------------
// prep: node1/node2 fp32 (for fallback) + bf16 hi/lo splits (for MFMA path)
// ---------------------------------------------------------------------------
__global__ __launch_bounds__(256) void prep_nodes(
    const float* __restrict__ emb, const float* __restrict__ w1w,
    const float* __restrict__ w1b, const float* __restrict__ w2w,
    const float* __restrict__ w2b, float* __restrict__ n1f,
    float* __restrict__ n2f, unsigned short* __restrict__ n1hi,
    unsigned short* __restrict__ n1lo, unsigned short* __restrict__ n2hi,
    unsigned short* __restrict__ n2lo, int wantbf)
{
  __shared__ float wl[2][DD][DD];
  int t = threadIdx.x;
  for (int i = t; i < DD * DD; i += 256) {
    wl[0][i >> 6][i & 63] = w1w[i];
    wl[1][i >> 6][i & 63] = w2w[i];
  }
  __syncthreads();
  int g = blockIdx.x * 256 + t;
  int which = (g >= NN * DD) ? 1 : 0;
  int idx = which ? g - NN * DD : g;
  int n = idx >> 6, d = idx & 63;
  const float* e = emb + (size_t)n * DD;
  float s = which ? w2b[d] : w1b[d];
  #pragma unroll
  for (int k = 0; k < DD; ++k) s += e[k] * wl[which][d][k];
  (which ? n2f : n1f)[idx] = s;
  if (wantbf) {
    unsigned short hi = f2bf(s);
    unsigned short lo = f2bf(s - bf2f(hi));
    (which ? n2hi : n1hi)[idx] = hi;
    (which ? n2lo : n1lo)[idx] = lo;
  }
}

// ---------------------------------------------------------------------------
// prep: x -> bf16 hi/lo split arrays, fused with v[b,n] = x[b,n,:].wp + wp_b
// ---------------------------------------------------------------------------
__global__ __launch_bounds__(256) void prep_x(
    const float* __restrict__ x, const float* __restrict__ wpw,
    const float* __restrict__ wpb, unsigned short* __restrict__ xhi,
    unsigned short* __restrict__ xlo, float* __restrict__ v)
{
  int t = threadIdx.x;
  int g = blockIdx.x * 256 + t;
  int e0 = g * 4;
  float4 xx = *(const float4*)&x[e0];
  ushort4 hi, lo;
  hi.x = f2bf(xx.x); lo.x = f2bf(xx.x - bf2f(hi.x));
  hi.y = f2bf(xx.y); lo.y = f2bf(xx.y - bf2f(hi.y));
  hi.z = f2bf(xx.z); lo.z = f2bf(xx.z - bf2f(hi.z));
  hi.w = f2bf(xx.w); lo.w = f2bf(xx.w - bf2f(hi.w));
  *(ushort4*)&xhi[e0] = hi;
  *(ushort4*)&xlo[e0] = lo;
  float4 wq = *(const float4*)&wpw[(t & 15) * 4];
  float s = xx.x * wq.x + xx.y * wq.y + xx.z * wq.z + xx.w * wq.w;
  s += __shfl_xor(s, 1, 64);
  s += __shfl_xor(s, 2, 64);
  s += __shfl_xor(s, 4, 64);
  s += __shfl_xor(s, 8, 64);
  if ((t & 15) == 0) v[g >> 4] = s + wpb[0];
}

// ---------------------------------------------------------------------------
// prep_v kept for the small-ws fallback path only
// ---------------------------------------------------------------------------
__global__ __launch_bounds__(256) void prep_v(
    const float* __restrict__ x, const float* __restrict__ wpw,
    const float* __restrict__ wpb, float* __restrict__ v)
{
  int g = blockIdx.x * 256 + threadIdx.x;
  const float* xr = x + (size_t)g * DD;
  float s = wpb[0];
  #pragma unroll
  for (int kq = 0; kq < DD / 4; ++kq) {
    float4 q = *(const float4*)&xr[kq * 4];
    float4 w = *(const float4*)&wpw[kq * 4];
    s += q.x * w.x + q.y * w.y + q.z * w.z + q.w * w.w;
  }
  v[g] = s;
}

// ---------------------------------------------------------------------------
// base = relu(n1 @ n2^T) via split-bf16 MFMA.
// grid (128 row-blocks, 8 col-chunks): 1024 blocks, wave owns 16 rows x 64 cols
// ---------------------------------------------------------------------------
__global__ __launch_bounds__(256) void base_mfma(
    const unsigned short* __restrict__ n1hi, const unsigned short* __restrict__ n1lo,
    const unsigned short* __restrict__ n2hi, const unsigned short* __restrict__ n2lo,
    float* __restrict__ base)
{
  int t = threadIdx.x, lane = t & 63, w = t >> 6;
  int q = lane >> 4, m = lane & 15;
  int n0 = blockIdx.x * 16;
  int cw = blockIdx.y * 256 + w * 64;
  int aidx = (n0 + m) * DD + q * 8;
  bf16x8 ah0 = ldfrag(n1hi + aidx), ah1 = ldfrag(n1hi + aidx + 32);
  bf16x8 al0 = ldfrag(n1lo + aidx), al1 = ldfrag(n1lo + aidx + 32);
  #pragma unroll
  for (int tt = 0; tt < 4; ++tt) {
    int c = cw + tt * 16 + m;
    size_t bidx = (size_t)c * DD + q * 8;
    bf16x8 bh0 = ldfrag(n2hi + bidx), bh1 = ldfrag(n2hi + bidx + 32);
    bf16x8 bl0 = ldfrag(n2lo + bidx), bl1 = ldfrag(n2lo + bidx + 32);
    f32x4 a = {0.f, 0.f, 0.f, 0.f};
    f32x4 bq = {0.f, 0.f, 0.f, 0.f};
    a = MFMA16(ah0, bh0, a, 0, 0, 0);
    a = MFMA16(ah1, bh1, a, 0, 0, 0);
    bq = MFMA16(ah0, bl0, bq, 0, 0, 0);
    bq = MFMA16(ah1, bl1, bq, 0, 0, 0);
    bq = MFMA16(al0, bh0, bq, 0, 0, 0);
    bq = MFMA16(al1, bh1, bq, 0, 0, 0);
    #pragma unroll
    for (int r = 0; r < 4; ++r)
      base[(size_t)(n0 + q * 4 + r) * NN + c] = fmaxf(a[r] + bq[r], 0.f);
  }
}

// ---------------------------------------------------------------------------
// fused: single-pass, acc held in regs. 8 waves x (16 rows x 256 cols).
// acc[16][4] = 64 regs (half of round-0's 128) -> 2 blocks/CU instead of <1.
// Two independent MFMA accumulators per tile (hh | hl+lh) to break the
// 6-deep serial accumulation chain.
// C/D layout: col = lane&15, row = (lane>>4)*4 + reg.
// ---------------------------------------------------------------------------
__global__ __launch_bounds__(512, 4) void fused_mfma(
    const unsigned short* __restrict__ xhi, const unsigned short* __restrict__ xlo,
    const float* __restrict__ base, const float* __restrict__ vv,
    float* __restrict__ out)
{
  __shared__ float redm[FW][16];
  __shared__ float reds[FW][16];
  int t = threadIdx.x, lane = t & 63, w = t >> 6;
  int q = lane >> 4, m = lane & 15;
  int b = blockIdx.y, n0 = blockIdx.x * 16, cw = w * (FT * 16);
  size_t xb = (size_t)b * NN * DD;

  int aoff = (n0 + m) * DD + q * 8;
  bf16x8 ah0 = ldfrag(xhi + xb + aoff), ah1 = ldfrag(xhi + xb + aoff + 32);
  bf16x8 al0 = ldfrag(xlo + xb + aoff), al1 = ldfrag(xlo + xb + aoff + 32);

  float vrow[4];
  #pragma unroll
  for (int r = 0; r < 4; ++r) vrow[r] = vv[b * NN + n0 + q * 4 + r];

  f32x4 acc[FT];
  #pragma unroll
  for (int tt = 0; tt < FT; ++tt) {
    int c = cw + tt * 16 + m;
    size_t bidx = xb + (size_t)c * DD + q * 8;
    bf16x8 bh0 = ldfrag(xhi + bidx), bh1 = ldfrag(xhi + bidx + 32);
    bf16x8 bl0 = ldfrag(xlo + bidx), bl1 = ldfrag(xlo + bidx + 32);
    f32x4 a = {0.f, 0.f, 0.f, 0.f};
    f32x4 bq = {0.f, 0.f, 0.f, 0.f};
    a = MFMA16(ah0, bh0, a, 0, 0, 0);
    a = MFMA16(ah1, bh1, a, 0, 0, 0);
    bq = MFMA16(ah0, bl0, bq, 0, 0, 0);
    bq = MFMA16(ah1, bl1, bq, 0, 0, 0);
    bq = MFMA16(al0, bh0, bq, 0, 0, 0);
    bq = MFMA16(al1, bh1, bq, 0, 0, 0);
    float vc = vv[b * NN + c];
    #pragma unroll
    for (int r = 0; r < 4; ++r)
      a[r] += bq[r] + base[(size_t)(n0 + q * 4 + r) * NN + c] + vrow[r] - vc;
    acc[tt] = a;
  }

  // row max: per-lane over tiles, shuffle across the 16 column-lanes,
  // then cross-wave via LDS
  float mx[4];
  #pragma unroll
  for (int r = 0; r < 4; ++r) mx[r] = acc[0][r];
  #pragma unroll
  for (int tt = 1; tt < FT; ++tt)
    #pragma unroll
    for (int r = 0; r < 4; ++r) mx[r] = fmaxf(mx[r], acc[tt][r]);
  #pragma unroll
  for (int off = 8; off >= 1; off >>= 1)
    #pragma unroll
    for (int r = 0; r < 4; ++r) mx[r] = fmaxf(mx[r], __shfl_xor(mx[r], off, 64));
  if (m == 0) {
    #pragma unroll
    for (int r = 0; r < 4; ++r) redm[w][q * 4 + r] = mx[r];
  }
  __syncthreads();
  float mrow[4], sm[4];
  #pragma unroll
  for (int r = 0; r < 4; ++r) {
    int rr = q * 4 + r;
    float mv = redm[0][rr];
    #pragma unroll
    for (int ww = 1; ww < FW; ++ww) mv = fmaxf(mv, redm[ww][rr]);
    mrow[r] = mv;
    sm[r] = 0.f;
  }
  #pragma unroll
  for (int tt = 0; tt < FT; ++tt)
    #pragma unroll
    for (int r = 0; r < 4; ++r) {
      float e = __expf(acc[tt][r] - mrow[r]);
      acc[tt][r] = e;
      sm[r] += e;
    }
  #pragma unroll
  for (int off = 8; off >= 1; off >>= 1)
    #pragma unroll
    for (int r = 0; r < 4; ++r) sm[r] += __shfl_xor(sm[r], off, 64);
  if (m == 0) {
    #pragma unroll
    for (int r = 0; r < 4; ++r) reds[w][q * 4 + r] = sm[r];
  }
  __syncthreads();
  float inv[4];
  #pragma unroll
  for (int r = 0; r < 4; ++r) {
    int rr = q * 4 + r;
    float sv = reds[0][rr];
    #pragma unroll
    for (int ww = 1; ww < FW; ++ww) sv += reds[ww][rr];
    inv[r] = 1.f / sv;
  }
  // tight store burst (plain stores: full lines get assembled in L2)
  #pragma unroll
  for (int tt = 0; tt < FT; ++tt) {
    int c = cw + tt * 16 + m;
    #pragma unroll
    for (int r = 0; r < 4; ++r)
      out[((size_t)b * NN + n0 + q * 4 + r) * NN + c] = acc[tt][r] * inv[r];
  }
}

// ---------------------------------------------------------------------------
// small-ws fallback (R1 VALU path, recomputes base dot per block)
// ---------------------------------------------------------------------------
__global__ __launch_bounds__(256) void fused_fallback(
    const float* __restrict__ x, const float* __restrict__ node1,
    const float* __restrict__ node2, const float* __restrict__ vv,
    float* __restrict__ out)
{
  __shared__ float xr[TM][DD];
  __shared__ float n1r[TM][DD];
  __shared__ float colbuf[2][DD / 2][MC + 1];
  __shared__ float redm[4][4];
  __shared__ float reds[4][4];

  int t = threadIdx.x;
  int b = blockIdx.y;
  int n0 = blockIdx.x * TM;
  int mloc = t & (MC - 1);
  int grp = t >> 7;
  int r0 = grp * 4;

  for (int i = t; i < TM * DD; i += 256) {
    xr[i >> 6][i & 63] = x[((size_t)b * NN + n0) * DD + i];
    n1r[i >> 6][i & 63] = node1[(size_t)n0 * DD + i];
  }
  float vrow[4];
  #pragma unroll
  for (int r = 0; r < 4; ++r) vrow[r] = vv[b * NN + n0 + r0 + r];

  float acc[4][NCH];

  #pragma unroll
  for (int c = 0; c < NCH; ++c) {
    float dacc[4] = {0.f, 0.f, 0.f, 0.f};
    float bacc[4] = {0.f, 0.f, 0.f, 0.f};
    #pragma unroll
    for (int h = 0; h < 2; ++h) {
      __syncthreads();
      #pragma unroll
      for (int i = 0; i < 8; ++i) {
        int f = i * 256 + t;
        int arr = f >> 10;
        int ff = f & 1023;
        int mm = ff >> 3, kq = ff & 7;
        const float* src = arr
            ? node2 + (size_t)(c * MC + mm) * DD + h * 32 + kq * 4
            : x + ((size_t)b * NN + c * MC + mm) * DD + h * 32 + kq * 4;
        float4 qv = *(const float4*)src;
        colbuf[arr][kq * 4 + 0][mm] = qv.x;
        colbuf[arr][kq * 4 + 1][mm] = qv.y;
        colbuf[arr][kq * 4 + 2][mm] = qv.z;
        colbuf[arr][kq * 4 + 3][mm] = qv.w;
      }
      __syncthreads();
      #pragma unroll
      for (int kb = 0; kb < 8; ++kb) {
        float ra[4][4], rb[4][4];
        #pragma unroll
        for (int r = 0; r < 4; ++r) {
          float4 qx = *(const float4*)&xr[r0 + r][h * 32 + kb * 4];
          ra[r][0] = qx.x; ra[r][1] = qx.y; ra[r][2] = qx.z; ra[r][3] = qx.w;
          float4 qn = *(const float4*)&n1r[r0 + r][h * 32 + kb * 4];
          rb[r][0] = qn.x; rb[r][1] = qn.y; rb[r][2] = qn.z; rb[r][3] = qn.w;
        }
        #pragma unroll
        for (int kk = 0; kk < 4; ++kk) {
          float cx = colbuf[0][kb * 4 + kk][mloc];
          float cn = colbuf[1][kb * 4 + kk][mloc];
          #pragma unroll
          for (int r = 0; r < 4; ++r) {
            dacc[r] += ra[r][kk] * cx;
            bacc[r] += rb[r][kk] * cn;
          }
        }
      }
    }
    float vc = vv[b * NN + c * MC + mloc];
    #pragma unroll
    for (int r = 0; r < 4; ++r)
      acc[r][c] = dacc[r] + vrow[r] - vc + fmaxf(bacc[r], 0.f);
  }

  float pm[4];
  #pragma unroll
  for (int r = 0; r < 4; ++r) {
    float mv = acc[r][0];
    #pragma unroll
    for (int c = 1; c < NCH; ++c) mv = fmaxf(mv, acc[r][c]);
    #pragma unroll
    for (int off = 32; off >= 1; off >>= 1)
      mv = fmaxf(mv, __shfl_xor(mv, off, 64));
    pm[r] = mv;
  }
  int w = t >> 6;
  if ((t & 63) == 0) {
    #pragma unroll
    for (int r = 0; r < 4; ++r) redm[w][r] = pm[r];
  }
  __syncthreads();
  float mrow[4], ps[4];
  #pragma unroll
  for (int r = 0; r < 4; ++r) {
    mrow[r] = fmaxf(redm[grp * 2][r], redm[grp * 2 + 1][r]);
    ps[r] = 0.f;
  }
  #pragma unroll
  for (int c = 0; c < NCH; ++c)
    #pragma unroll
    for (int r = 0; r < 4; ++r) {
      float e = __expf(acc[r][c] - mrow[r]);
      acc[r][c] = e;
      ps[r] += e;
    }
  #pragma unroll
  for (int r = 0; r < 4; ++r)
    #pragma unroll
    for (int off = 32; off >= 1; off >>= 1)
      ps[r] += __shfl_xor(ps[r], off, 64);
  if ((t & 63) == 0) {
    #pragma unroll
    for (int r = 0; r < 4; ++r) reds[w][r] = ps[r];
  }
  __syncthreads();
  float inv[4];
  #pragma unroll
  for (int r = 0; r < 4; ++r)
    inv[r] = 1.f / (reds[grp * 2][r] + reds[grp * 2 + 1][r]);
  #pragma unroll
  for (int c = 0; c < NCH; ++c)
    #pragma unroll
    for (int r = 0; r < 4; ++r)
      out[((size_t)b * NN + n0 + r0 + r) * NN + c * MC + mloc] = acc[r][c] * inv[r];
}

// ---------------------------------------------------------------------------
extern "C" void kernel_launch(void* const* d_in, const int* in_sizes, int n_in,
                              void* d_out, int out_size, void* d_ws, size_t ws_size,
                              hipStream_t stream)
{
  const float* x   = (const float*)d_in[0];
  const float* emb = (const float*)d_in[1];
  const float* w1w = (const float*)d_in[2];
  const float* w1b = (const float*)d_in[3];
  const float* w2w = (const float*)d_in[4];
  const float* w2b = (const float*)d_in[5];
  const float* wpw = (const float*)d_in[6];
  const float* wpb = (const float*)d_in[7];
  float* out = (float*)d_out;

  float* wsf   = (float*)d_ws;
  float* node1 = wsf;
  float* node2 = wsf + (size_t)NN * DD;
  float* v     = wsf + (size_t)2 * NN * DD;
  float* base  = wsf + (size_t)2 * NN * DD + (size_t)BB * NN;
  unsigned short* bfb = (unsigned short*)(base + (size_t)NN * NN);
  unsigned short* xhi = bfb;
  unsigned short* xlo = xhi + (size_t)BB * NN * DD;
  unsigned short* n1hi = xlo + (size_t)BB * NN * DD;
  unsigned short* n1lo = n1hi + (size_t)NN * DD;
  unsigned short* n2hi = n1lo + (size_t)NN * DD;
  unsigned short* n2lo = n2hi + (size_t)NN * DD;

  size_t need_mfma = ((size_t)2 * NN * DD + (size_t)BB * NN + (size_t)NN * NN) * 4
                   + ((size_t)2 * BB * NN * DD + (size_t)4 * NN * DD) * 2;
  bool big = ws_size >= need_mfma;

  prep_nodes<<<2 * NN * DD / 256, 256, 0, stream>>>(
      emb, w1w, w1b, w2w, w2b, node1, node2, n1hi, n1lo, n2hi, n2lo, big ? 1 : 0);

  if (big) {
    prep_x<<<BB * NN * DD / 4 / 256, 256, 0, stream>>>(x, wpw, wpb, xhi, xlo, v);
    dim3 bgrid(NN / 16, 8);
    base_mfma<<<bgrid, 256, 0, stream>>>(n1hi, n1lo, n2hi, n2lo, base);
    dim3 grid(NN / 16, BB);
    fused_mfma<<<grid, 512, 0, stream>>>(xhi, xlo, base, v, out);
  } else {
    prep_v<<<BB * NN / 256, 256, 0, stream>>>(x, wpw, wpb, v);
    dim3 grid(NN / TM, BB);
    fused_fallback<<<grid, 256, 0, stream>>>(x, node1, node2, v, out);
  }
}

// Round 3
// 389.556 us; speedup vs baseline: 1.4545x; 1.1475x over previous
//
#include <hip/hip_runtime.h>

#define BB 16
#define NN 2048
#define DD 64
#define MC 128
#define NCH (NN / MC)
#define TM 8

// fused_mfma geometry: 512 threads = 8 waves, wave owns 16 rows x 256 cols
#define FW 8          // waves per block
#define FT 16         // 16x16 tiles per wave (256 cols)

// MFMA-tiled bf16 layout: elem (n,k) -> (n>>4)*1024 + (k>>3)*128 + (n&15)*8 + (k&7)
// => fragment load for tile t0 (rows/cols t0..t0+15) is ldfrag(base + t0*64 + lane*8)
//    for k=0..31, and +512 for k=32..63. Fully coalesced: 64 lanes x 16B contiguous.

typedef __bf16 bf16x8 __attribute__((ext_vector_type(8)));
typedef float f32x4 __attribute__((ext_vector_type(4)));
typedef int i32x4 __attribute__((ext_vector_type(4)));
typedef unsigned short u16x8 __attribute__((ext_vector_type(8)));

#define MFMA16 __builtin_amdgcn_mfma_f32_16x16x32_bf16

__device__ inline unsigned short f2bf(float f) {
  unsigned u = __float_as_uint(f);
  unsigned r = u + 0x7FFFu + ((u >> 16) & 1u);
  return (unsigned short)(r >> 16);
}
__device__ inline float bf2f(unsigned short h) {
  return __uint_as_float(((unsigned)h) << 16);
}
__device__ inline bf16x8 ldfrag(const unsigned short* p) {
  i32x4 v = *reinterpret_cast<const i32x4*>(p);
  return __builtin_bit_cast(bf16x8, v);
}

// ---------------------------------------------------------------------------
// prep: node1/node2 fp32 (for fallback) + bf16 hi/lo splits in TILED layout
// wl padded to 65 to kill the 32-way LDS bank conflict (stride-64 reads)
// ---------------------------------------------------------------------------
__global__ __launch_bounds__(256) void prep_nodes(
    const float* __restrict__ emb, const float* __restrict__ w1w,
    const float* __restrict__ w1b, const float* __restrict__ w2w,
    const float* __restrict__ w2b, float* __restrict__ n1f,
    float* __restrict__ n2f, unsigned short* __restrict__ n1hi,
    unsigned short* __restrict__ n1lo, unsigned short* __restrict__ n2hi,
    unsigned short* __restrict__ n2lo, int wantbf)
{
  __shared__ float wl[2][DD][DD + 1];
  int t = threadIdx.x;
  for (int i = t; i < DD * DD; i += 256) {
    wl[0][i >> 6][i & 63] = w1w[i];
    wl[1][i >> 6][i & 63] = w2w[i];
  }
  __syncthreads();
  int g = blockIdx.x * 256 + t;
  int which = (g >= NN * DD) ? 1 : 0;
  int idx = which ? g - NN * DD : g;
  int n = idx >> 6, d = idx & 63;
  const float* e = emb + (size_t)n * DD;
  float s = which ? w2b[d] : w1b[d];
  #pragma unroll
  for (int k = 0; k < DD; ++k) s += e[k] * wl[which][d][k];
  (which ? n2f : n1f)[idx] = s;
  if (wantbf) {
    unsigned short hi = f2bf(s);
    unsigned short lo = f2bf(s - bf2f(hi));
    int ti = (n >> 4) * 1024 + (d >> 3) * 128 + (n & 15) * 8 + (d & 7);
    (which ? n2hi : n1hi)[ti] = hi;
    (which ? n2lo : n1lo)[ti] = lo;
  }
}

// ---------------------------------------------------------------------------
// prep: x -> bf16 hi/lo splits in TILED layout. One thread = one 8-k chunk,
// dest-linear thread mapping -> perfectly coalesced 16B stores.
// ---------------------------------------------------------------------------
__global__ __launch_bounds__(256) void prep_x(
    const float* __restrict__ x, unsigned short* __restrict__ xhi,
    unsigned short* __restrict__ xlo)
{
  int G = blockIdx.x * 256 + threadIdx.x;
  int b = G >> 14;            // NN*DD/8 = 16384 chunks per batch
  int rem = G & 16383;
  int tile = rem >> 7, oct = (rem >> 4) & 7, m = rem & 15;
  const float* src = x + ((size_t)b * NN + tile * 16 + m) * DD + oct * 8;
  float4 x0 = *(const float4*)src;
  float4 x1 = *(const float4*)(src + 4);
  u16x8 hv, lv;
  hv[0] = f2bf(x0.x); lv[0] = f2bf(x0.x - bf2f(hv[0]));
  hv[1] = f2bf(x0.y); lv[1] = f2bf(x0.y - bf2f(hv[1]));
  hv[2] = f2bf(x0.z); lv[2] = f2bf(x0.z - bf2f(hv[2]));
  hv[3] = f2bf(x0.w); lv[3] = f2bf(x0.w - bf2f(hv[3]));
  hv[4] = f2bf(x1.x); lv[4] = f2bf(x1.x - bf2f(hv[4]));
  hv[5] = f2bf(x1.y); lv[5] = f2bf(x1.y - bf2f(hv[5]));
  hv[6] = f2bf(x1.z); lv[6] = f2bf(x1.z - bf2f(hv[6]));
  hv[7] = f2bf(x1.w); lv[7] = f2bf(x1.w - bf2f(hv[7]));
  *(u16x8*)&xhi[(size_t)G * 8] = hv;
  *(u16x8*)&xlo[(size_t)G * 8] = lv;
}

// ---------------------------------------------------------------------------
// prep: v[b,n] = x[b,n,:] . wp + wp_b (both paths)
// ---------------------------------------------------------------------------
__global__ __launch_bounds__(256) void prep_v(
    const float* __restrict__ x, const float* __restrict__ wpw,
    const float* __restrict__ wpb, float* __restrict__ v)
{
  int g = blockIdx.x * 256 + threadIdx.x;
  const float* xr = x + (size_t)g * DD;
  float s = wpb[0];
  #pragma unroll
  for (int kq = 0; kq < DD / 4; ++kq) {
    float4 q = *(const float4*)&xr[kq * 4];
    float4 w = *(const float4*)&wpw[kq * 4];
    s += q.x * w.x + q.y * w.y + q.z * w.z + q.w * w.w;
  }
  v[g] = s;
}

// ---------------------------------------------------------------------------
// base = relu(n1 @ n2^T), tiled-layout fragment loads (all coalesced)
// grid (128 row-blocks, 8 col-chunks), wave owns 16 rows x 64 cols
// ---------------------------------------------------------------------------
__global__ __launch_bounds__(256) void base_mfma(
    const unsigned short* __restrict__ n1hi, const unsigned short* __restrict__ n1lo,
    const unsigned short* __restrict__ n2hi, const unsigned short* __restrict__ n2lo,
    float* __restrict__ base)
{
  int t = threadIdx.x, lane = t & 63, w = t >> 6;
  int q = lane >> 4, m = lane & 15;
  int n0 = blockIdx.x * 16;
  int cw = blockIdx.y * 256 + w * 64;
  int la8 = lane * 8;
  bf16x8 ah0 = ldfrag(n1hi + n0 * 64 + la8), ah1 = ldfrag(n1hi + n0 * 64 + 512 + la8);
  bf16x8 al0 = ldfrag(n1lo + n0 * 64 + la8), al1 = ldfrag(n1lo + n0 * 64 + 512 + la8);
  #pragma unroll
  for (int tt = 0; tt < 4; ++tt) {
    int c0 = cw + tt * 16;
    bf16x8 bh0 = ldfrag(n2hi + c0 * 64 + la8), bh1 = ldfrag(n2hi + c0 * 64 + 512 + la8);
    bf16x8 bl0 = ldfrag(n2lo + c0 * 64 + la8), bl1 = ldfrag(n2lo + c0 * 64 + 512 + la8);
    f32x4 a = {0.f, 0.f, 0.f, 0.f};
    f32x4 bq = {0.f, 0.f, 0.f, 0.f};
    a = MFMA16(ah0, bh0, a, 0, 0, 0);
    a = MFMA16(ah1, bh1, a, 0, 0, 0);
    bq = MFMA16(ah0, bl0, bq, 0, 0, 0);
    bq = MFMA16(ah1, bl1, bq, 0, 0, 0);
    bq = MFMA16(al0, bh0, bq, 0, 0, 0);
    bq = MFMA16(al1, bh1, bq, 0, 0, 0);
    #pragma unroll
    for (int r = 0; r < 4; ++r)
      base[(size_t)(n0 + q * 4 + r) * NN + c0 + m] = fmaxf(a[r] + bq[r], 0.f);
  }
}

// ---------------------------------------------------------------------------
// fused: single-pass, acc in regs, tiled-layout fragment loads (coalesced).
// 8 waves x (16 rows x 256 cols). C/D layout: col = lane&15, row = (lane>>4)*4+reg.
// ---------------------------------------------------------------------------
__global__ __launch_bounds__(512, 4) void fused_mfma(
    const unsigned short* __restrict__ xhi, const unsigned short* __restrict__ xlo,
    const float* __restrict__ base, const float* __restrict__ vv,
    float* __restrict__ out)
{
  __shared__ float redm[FW][16];
  __shared__ float reds[FW][16];
  int t = threadIdx.x, lane = t & 63, w = t >> 6;
  int q = lane >> 4, m = lane & 15;
  int b = blockIdx.y, n0 = blockIdx.x * 16, cw = w * (FT * 16);
  size_t xb = (size_t)b * NN * DD;
  int la8 = lane * 8;

  const unsigned short* ah = xhi + xb + n0 * 64;
  const unsigned short* al = xlo + xb + n0 * 64;
  bf16x8 ah0 = ldfrag(ah + la8), ah1 = ldfrag(ah + 512 + la8);
  bf16x8 al0 = ldfrag(al + la8), al1 = ldfrag(al + 512 + la8);

  float vrow[4];
  #pragma unroll
  for (int r = 0; r < 4; ++r) vrow[r] = vv[b * NN + n0 + q * 4 + r];

  f32x4 acc[FT];
  #pragma unroll
  for (int tt = 0; tt < FT; ++tt) {
    int c0 = cw + tt * 16;
    const unsigned short* bh = xhi + xb + c0 * 64;
    const unsigned short* bl = xlo + xb + c0 * 64;
    bf16x8 bh0 = ldfrag(bh + la8), bh1 = ldfrag(bh + 512 + la8);
    bf16x8 bl0 = ldfrag(bl + la8), bl1 = ldfrag(bl + 512 + la8);
    f32x4 a = {0.f, 0.f, 0.f, 0.f};
    f32x4 bq = {0.f, 0.f, 0.f, 0.f};
    a = MFMA16(ah0, bh0, a, 0, 0, 0);
    a = MFMA16(ah1, bh1, a, 0, 0, 0);
    bq = MFMA16(ah0, bl0, bq, 0, 0, 0);
    bq = MFMA16(ah1, bl1, bq, 0, 0, 0);
    bq = MFMA16(al0, bh0, bq, 0, 0, 0);
    bq = MFMA16(al1, bh1, bq, 0, 0, 0);
    float vc = vv[b * NN + c0 + m];
    #pragma unroll
    for (int r = 0; r < 4; ++r)
      a[r] += bq[r] + base[(size_t)(n0 + q * 4 + r) * NN + c0 + m] + vrow[r] - vc;
    acc[tt] = a;
  }

  // row max: per-lane over tiles, shuffle across 16 column-lanes, cross-wave LDS
  float mx[4];
  #pragma unroll
  for (int r = 0; r < 4; ++r) mx[r] = acc[0][r];
  #pragma unroll
  for (int tt = 1; tt < FT; ++tt)
    #pragma unroll
    for (int r = 0; r < 4; ++r) mx[r] = fmaxf(mx[r], acc[tt][r]);
  #pragma unroll
  for (int off = 8; off >= 1; off >>= 1)
    #pragma unroll
    for (int r = 0; r < 4; ++r) mx[r] = fmaxf(mx[r], __shfl_xor(mx[r], off, 64));
  if (m == 0) {
    #pragma unroll
    for (int r = 0; r < 4; ++r) redm[w][q * 4 + r] = mx[r];
  }
  __syncthreads();
  float mrow[4], sm[4];
  #pragma unroll
  for (int r = 0; r < 4; ++r) {
    int rr = q * 4 + r;
    float mv = redm[0][rr];
    #pragma unroll
    for (int ww = 1; ww < FW; ++ww) mv = fmaxf(mv, redm[ww][rr]);
    mrow[r] = mv;
    sm[r] = 0.f;
  }
  #pragma unroll
  for (int tt = 0; tt < FT; ++tt)
    #pragma unroll
    for (int r = 0; r < 4; ++r) {
      float e = __expf(acc[tt][r] - mrow[r]);
      acc[tt][r] = e;
      sm[r] += e;
    }
  #pragma unroll
  for (int off = 8; off >= 1; off >>= 1)
    #pragma unroll
    for (int r = 0; r < 4; ++r) sm[r] += __shfl_xor(sm[r], off, 64);
  if (m == 0) {
    #pragma unroll
    for (int r = 0; r < 4; ++r) reds[w][q * 4 + r] = sm[r];
  }
  __syncthreads();
  float inv[4];
  #pragma unroll
  for (int r = 0; r < 4; ++r) {
    int rr = q * 4 + r;
    float sv = reds[0][rr];
    #pragma unroll
    for (int ww = 1; ww < FW; ++ww) sv += reds[ww][rr];
    inv[r] = 1.f / sv;
  }
  #pragma unroll
  for (int tt = 0; tt < FT; ++tt) {
    int c = cw + tt * 16 + m;
    #pragma unroll
    for (int r = 0; r < 4; ++r)
      out[((size_t)b * NN + n0 + q * 4 + r) * NN + c] = acc[tt][r] * inv[r];
  }
}

// ---------------------------------------------------------------------------
// small-ws fallback (R1 VALU path, recomputes base dot per block)
// ---------------------------------------------------------------------------
__global__ __launch_bounds__(256) void fused_fallback(
    const float* __restrict__ x, const float* __restrict__ node1,
    const float* __restrict__ node2, const float* __restrict__ vv,
    float* __restrict__ out)
{
  __shared__ float xr[TM][DD];
  __shared__ float n1r[TM][DD];
  __shared__ float colbuf[2][DD / 2][MC + 1];
  __shared__ float redm[4][4];
  __shared__ float reds[4][4];

  int t = threadIdx.x;
  int b = blockIdx.y;
  int n0 = blockIdx.x * TM;
  int mloc = t & (MC - 1);
  int grp = t >> 7;
  int r0 = grp * 4;

  for (int i = t; i < TM * DD; i += 256) {
    xr[i >> 6][i & 63] = x[((size_t)b * NN + n0) * DD + i];
    n1r[i >> 6][i & 63] = node1[(size_t)n0 * DD + i];
  }
  float vrow[4];
  #pragma unroll
  for (int r = 0; r < 4; ++r) vrow[r] = vv[b * NN + n0 + r0 + r];

  float acc[4][NCH];

  #pragma unroll
  for (int c = 0; c < NCH; ++c) {
    float dacc[4] = {0.f, 0.f, 0.f, 0.f};
    float bacc[4] = {0.f, 0.f, 0.f, 0.f};
    #pragma unroll
    for (int h = 0; h < 2; ++h) {
      __syncthreads();
      #pragma unroll
      for (int i = 0; i < 8; ++i) {
        int f = i * 256 + t;
        int arr = f >> 10;
        int ff = f & 1023;
        int mm = ff >> 3, kq = ff & 7;
        const float* src = arr
            ? node2 + (size_t)(c * MC + mm) * DD + h * 32 + kq * 4
            : x + ((size_t)b * NN + c * MC + mm) * DD + h * 32 + kq * 4;
        float4 qv = *(const float4*)src;
        colbuf[arr][kq * 4 + 0][mm] = qv.x;
        colbuf[arr][kq * 4 + 1][mm] = qv.y;
        colbuf[arr][kq * 4 + 2][mm] = qv.z;
        colbuf[arr][kq * 4 + 3][mm] = qv.w;
      }
      __syncthreads();
      #pragma unroll
      for (int kb = 0; kb < 8; ++kb) {
        float ra[4][4], rb[4][4];
        #pragma unroll
        for (int r = 0; r < 4; ++r) {
          float4 qx = *(const float4*)&xr[r0 + r][h * 32 + kb * 4];
          ra[r][0] = qx.x; ra[r][1] = qx.y; ra[r][2] = qx.z; ra[r][3] = qx.w;
          float4 qn = *(const float4*)&n1r[r0 + r][h * 32 + kb * 4];
          rb[r][0] = qn.x; rb[r][1] = qn.y; rb[r][2] = qn.z; rb[r][3] = qn.w;
        }
        #pragma unroll
        for (int kk = 0; kk < 4; ++kk) {
          float cx = colbuf[0][kb * 4 + kk][mloc];
          float cn = colbuf[1][kb * 4 + kk][mloc];
          #pragma unroll
          for (int r = 0; r < 4; ++r) {
            dacc[r] += ra[r][kk] * cx;
            bacc[r] += rb[r][kk] * cn;
          }
        }
      }
    }
    float vc = vv[b * NN + c * MC + mloc];
    #pragma unroll
    for (int r = 0; r < 4; ++r)
      acc[r][c] = dacc[r] + vrow[r] - vc + fmaxf(bacc[r], 0.f);
  }

  float pm[4];
  #pragma unroll
  for (int r = 0; r < 4; ++r) {
    float mv = acc[r][0];
    #pragma unroll
    for (int c = 1; c < NCH; ++c) mv = fmaxf(mv, acc[r][c]);
    #pragma unroll
    for (int off = 32; off >= 1; off >>= 1)
      mv = fmaxf(mv, __shfl_xor(mv, off, 64));
    pm[r] = mv;
  }
  int w = t >> 6;
  if ((t & 63) == 0) {
    #pragma unroll
    for (int r = 0; r < 4; ++r) redm[w][r] = pm[r];
  }
  __syncthreads();
  float mrow[4], ps[4];
  #pragma unroll
  for (int r = 0; r < 4; ++r) {
    mrow[r] = fmaxf(redm[grp * 2][r], redm[grp * 2 + 1][r]);
    ps[r] = 0.f;
  }
  #pragma unroll
  for (int c = 0; c < NCH; ++c)
    #pragma unroll
    for (int r = 0; r < 4; ++r) {
      float e = __expf(acc[r][c] - mrow[r]);
      acc[r][c] = e;
      ps[r] += e;
    }
  #pragma unroll
  for (int r = 0; r < 4; ++r)
    #pragma unroll
    for (int off = 32; off >= 1; off >>= 1)
      ps[r] += __shfl_xor(ps[r], off, 64);
  if ((t & 63) == 0) {
    #pragma unroll
    for (int r = 0; r < 4; ++r) reds[w][r] = ps[r];
  }
  __syncthreads();
  float inv[4];
  #pragma unroll
  for (int r = 0; r < 4; ++r)
    inv[r] = 1.f / (reds[grp * 2][r] + reds[grp * 2 + 1][r]);
  #pragma unroll
  for (int c = 0; c < NCH; ++c)
    #pragma unroll
    for (int r = 0; r < 4; ++r)
      out[((size_t)b * NN + n0 + r0 + r) * NN + c * MC + mloc] = acc[r][c] * inv[r];
}

// ---------------------------------------------------------------------------
extern "C" void kernel_launch(void* const* d_in, const int* in_sizes, int n_in,
                              void* d_out, int out_size, void* d_ws, size_t ws_size,
                              hipStream_t stream)
{
  const float* x   = (const float*)d_in[0];
  const float* emb = (const float*)d_in[1];
  const float* w1w = (const float*)d_in[2];
  const float* w1b = (const float*)d_in[3];
  const float* w2w = (const float*)d_in[4];
  const float* w2b = (const float*)d_in[5];
  const float* wpw = (const float*)d_in[6];
  const float* wpb = (const float*)d_in[7];
  float* out = (float*)d_out;

  float* wsf   = (float*)d_ws;
  float* node1 = wsf;
  float* node2 = wsf + (size_t)NN * DD;
  float* v     = wsf + (size_t)2 * NN * DD;
  float* base  = wsf + (size_t)2 * NN * DD + (size_t)BB * NN;
  unsigned short* bfb = (unsigned short*)(base + (size_t)NN * NN);
  unsigned short* xhi = bfb;
  unsigned short* xlo = xhi + (size_t)BB * NN * DD;
  unsigned short* n1hi = xlo + (size_t)BB * NN * DD;
  unsigned short* n1lo = n1hi + (size_t)NN * DD;
  unsigned short* n2hi = n1lo + (size_t)NN * DD;
  unsigned short* n2lo = n2hi + (size_t)NN * DD;

  size_t need_mfma = ((size_t)2 * NN * DD + (size_t)BB * NN + (size_t)NN * NN) * 4
                   + ((size_t)2 * BB * NN * DD + (size_t)4 * NN * DD) * 2;
  bool big = ws_size >= need_mfma;

  prep_nodes<<<2 * NN * DD / 256, 256, 0, stream>>>(
      emb, w1w, w1b, w2w, w2b, node1, node2, n1hi, n1lo, n2hi, n2lo, big ? 1 : 0);
  prep_v<<<BB * NN / 256, 256, 0, stream>>>(x, wpw, wpb, v);

  if (big) {
    prep_x<<<BB * NN * DD / 8 / 256, 256, 0, stream>>>(x, xhi, xlo);
    dim3 bgrid(NN / 16, 8);
    base_mfma<<<bgrid, 256, 0, stream>>>(n1hi, n1lo, n2hi, n2lo, base);
    dim3 grid(NN / 16, BB);
    fused_mfma<<<grid, 512, 0, stream>>>(xhi, xlo, base, v, out);
  } else {
    dim3 grid(NN / TM, BB);
    fused_fallback<<<grid, 256, 0, stream>>>(x, node1, node2, v, out);
  }
}

// Round 4
// 338.912 us; speedup vs baseline: 1.6718x; 1.1494x over previous
//
#include <hip/hip_runtime.h>

#define BB 16
#define NN 2048
#define DD 64
#define MC 128
#define NCH (NN / MC)
#define TM 8

// fused_mfma geometry: 512 threads = 8 waves, wave owns 16 rows x 256 cols
#define FW 8          // waves per block
#define FT 16         // 16x16 tiles per wave (256 cols)

// MFMA-tiled bf16 layout: elem (n,k) -> (n>>4)*1024 + (k>>3)*128 + (n&15)*8 + (k&7)
// => fragment load for tile t0 is ldfrag(base + t0*64 + lane*8) for k=0..31,
//    +512 for k=32..63. Fully coalesced: 64 lanes x 16B contiguous.
// Tiled base (f32) layout: tile (rt,ct), lane -> ((rt*128+ct)*64 + lane)*4,
// f32x4 = rows q*4..q*4+3 of col ct*16+m (exact MFMA C/D register layout).

typedef __bf16 bf16x8 __attribute__((ext_vector_type(8)));
typedef float f32x4 __attribute__((ext_vector_type(4)));
typedef int i32x4 __attribute__((ext_vector_type(4)));
typedef unsigned short u16x8 __attribute__((ext_vector_type(8)));

#define MFMA16 __builtin_amdgcn_mfma_f32_16x16x32_bf16

__device__ inline unsigned short f2bf(float f) {
  unsigned u = __float_as_uint(f);
  unsigned r = u + 0x7FFFu + ((u >> 16) & 1u);
  return (unsigned short)(r >> 16);
}
__device__ inline float bf2f(unsigned short h) {
  return __uint_as_float(((unsigned)h) << 16);
}
__device__ inline bf16x8 ldfrag(const unsigned short* p) {
  i32x4 v = *reinterpret_cast<const i32x4*>(p);
  return __builtin_bit_cast(bf16x8, v);
}

// ---------------------------------------------------------------------------
// prep_all: one launch for {node splits, x splits, v}. Block-range dispatch:
//   [0,1024)    nodes: n1/n2 fp32 + tiled bf16 hi/lo splits
//   [1024,2048) x -> tiled bf16 hi/lo splits (skipped when !wantbf)
//   [2048,2176) v[b,n] = x . wp + wp_b
// ---------------------------------------------------------------------------
__global__ __launch_bounds__(256) void prep_all(
    const float* __restrict__ x, const float* __restrict__ emb,
    const float* __restrict__ w1w, const float* __restrict__ w1b,
    const float* __restrict__ w2w, const float* __restrict__ w2b,
    const float* __restrict__ wpw, const float* __restrict__ wpb,
    float* __restrict__ n1f, float* __restrict__ n2f,
    unsigned short* __restrict__ n1hi, unsigned short* __restrict__ n1lo,
    unsigned short* __restrict__ n2hi, unsigned short* __restrict__ n2lo,
    unsigned short* __restrict__ xhi, unsigned short* __restrict__ xlo,
    float* __restrict__ v, int wantbf)
{
  __shared__ float wl[2][DD][DD + 1];   // +1 pad: kills 64-way bank conflict
  int t = threadIdx.x, bx = blockIdx.x;

  if (bx < 1024) {
    for (int i = t; i < DD * DD; i += 256) {
      wl[0][i >> 6][i & 63] = w1w[i];
      wl[1][i >> 6][i & 63] = w2w[i];
    }
    __syncthreads();
    int g = bx * 256 + t;
    int which = (g >= NN * DD) ? 1 : 0;
    int idx = which ? g - NN * DD : g;
    int n = idx >> 6, d = idx & 63;
    const float* e = emb + (size_t)n * DD;
    float s = which ? w2b[d] : w1b[d];
    #pragma unroll
    for (int k = 0; k < DD; ++k) s += e[k] * wl[which][d][k];
    (which ? n2f : n1f)[idx] = s;
    if (wantbf) {
      unsigned short hi = f2bf(s);
      unsigned short lo = f2bf(s - bf2f(hi));
      int ti = (n >> 4) * 1024 + (d >> 3) * 128 + (n & 15) * 8 + (d & 7);
      (which ? n2hi : n1hi)[ti] = hi;
      (which ? n2lo : n1lo)[ti] = lo;
    }
  } else if (bx < 2048) {
    if (!wantbf) return;
    int G = (bx - 1024) * 256 + t;
    int b = G >> 14;            // NN*DD/8 = 16384 chunks per batch
    int rem = G & 16383;
    int tile = rem >> 7, oct = (rem >> 4) & 7, m = rem & 15;
    const float* src = x + ((size_t)b * NN + tile * 16 + m) * DD + oct * 8;
    float4 x0 = *(const float4*)src;
    float4 x1 = *(const float4*)(src + 4);
    u16x8 hv, lv;
    hv[0] = f2bf(x0.x); lv[0] = f2bf(x0.x - bf2f(hv[0]));
    hv[1] = f2bf(x0.y); lv[1] = f2bf(x0.y - bf2f(hv[1]));
    hv[2] = f2bf(x0.z); lv[2] = f2bf(x0.z - bf2f(hv[2]));
    hv[3] = f2bf(x0.w); lv[3] = f2bf(x0.w - bf2f(hv[3]));
    hv[4] = f2bf(x1.x); lv[4] = f2bf(x1.x - bf2f(hv[4]));
    hv[5] = f2bf(x1.y); lv[5] = f2bf(x1.y - bf2f(hv[5]));
    hv[6] = f2bf(x1.z); lv[6] = f2bf(x1.z - bf2f(hv[6]));
    hv[7] = f2bf(x1.w); lv[7] = f2bf(x1.w - bf2f(hv[7]));
    *(u16x8*)&xhi[(size_t)G * 8] = hv;
    *(u16x8*)&xlo[(size_t)G * 8] = lv;
  } else {
    int g = (bx - 2048) * 256 + t;
    const float* xr = x + (size_t)g * DD;
    float s = wpb[0];
    #pragma unroll
    for (int kq = 0; kq < DD / 4; ++kq) {
      float4 q = *(const float4*)&xr[kq * 4];
      float4 w = *(const float4*)&wpw[kq * 4];
      s += q.x * w.x + q.y * w.y + q.z * w.z + q.w * w.w;
    }
    v[g] = s;
  }
}

// ---------------------------------------------------------------------------
// base = relu(n1 @ n2^T), tiled fragment loads, TILED f32x4 stores
// (lane-contiguous dwordx4: 1 KB per store instruction).
// grid (128 row-blocks, 8 col-chunks), wave owns 16 rows x 64 cols.
// ---------------------------------------------------------------------------
__global__ __launch_bounds__(256) void base_mfma(
    const unsigned short* __restrict__ n1hi, const unsigned short* __restrict__ n1lo,
    const unsigned short* __restrict__ n2hi, const unsigned short* __restrict__ n2lo,
    float* __restrict__ baset)
{
  int t = threadIdx.x, lane = t & 63, w = t >> 6;
  int rt = blockIdx.x;
  int n0 = rt * 16;
  int cw = blockIdx.y * 256 + w * 64;
  int la8 = lane * 8;
  bf16x8 ah0 = ldfrag(n1hi + n0 * 64 + la8), ah1 = ldfrag(n1hi + n0 * 64 + 512 + la8);
  bf16x8 al0 = ldfrag(n1lo + n0 * 64 + la8), al1 = ldfrag(n1lo + n0 * 64 + 512 + la8);
  #pragma unroll
  for (int tt = 0; tt < 4; ++tt) {
    int c0 = cw + tt * 16;
    bf16x8 bh0 = ldfrag(n2hi + c0 * 64 + la8), bh1 = ldfrag(n2hi + c0 * 64 + 512 + la8);
    bf16x8 bl0 = ldfrag(n2lo + c0 * 64 + la8), bl1 = ldfrag(n2lo + c0 * 64 + 512 + la8);
    f32x4 a = {0.f, 0.f, 0.f, 0.f};
    f32x4 bq = {0.f, 0.f, 0.f, 0.f};
    a = MFMA16(ah0, bh0, a, 0, 0, 0);
    a = MFMA16(ah1, bh1, a, 0, 0, 0);
    bq = MFMA16(ah0, bl0, bq, 0, 0, 0);
    bq = MFMA16(ah1, bl1, bq, 0, 0, 0);
    bq = MFMA16(al0, bh0, bq, 0, 0, 0);
    bq = MFMA16(al1, bh1, bq, 0, 0, 0);
    f32x4 r4;
    #pragma unroll
    for (int r = 0; r < 4; ++r) r4[r] = fmaxf(a[r] + bq[r], 0.f);
    *(f32x4*)&baset[(((size_t)rt * 128 + (c0 >> 4)) * 64 + lane) * 4] = r4;
  }
}

// ---------------------------------------------------------------------------
// fused: single-pass, acc in regs, all loads tiled/coalesced.
// 1-D grid 2048, XCD-chunked swizzle decoded BATCH-MAJOR so each XCD works
// ~2 batches at a time -> per-XCD L2 hot set ~1.6 MB (B-frags become L2 hits).
// base read is one dwordx4 per tile (MFMA C-layout).
// C/D layout: col = lane&15, row = (lane>>4)*4 + reg.
// ---------------------------------------------------------------------------
__global__ __launch_bounds__(512, 4) void fused_mfma(
    const unsigned short* __restrict__ xhi, const unsigned short* __restrict__ xlo,
    const float* __restrict__ baset, const float* __restrict__ vv,
    float* __restrict__ out)
{
  __shared__ float redm[FW][16];
  __shared__ float reds[FW][16];
  int t = threadIdx.x, lane = t & 63, w = t >> 6;
  int q = lane >> 4, m = lane & 15;
  // bijective XCD-chunk swizzle (2048 % 8 == 0), batch-major decode
  int bid = blockIdx.x;
  int swz = (bid & 7) * 256 + (bid >> 3);
  int b = swz >> 7;
  int n0 = (swz & 127) * 16;
  int cw = w * (FT * 16);
  size_t xb = (size_t)b * NN * DD;
  int la8 = lane * 8;

  const unsigned short* ah = xhi + xb + n0 * 64;
  const unsigned short* al = xlo + xb + n0 * 64;
  bf16x8 ah0 = ldfrag(ah + la8), ah1 = ldfrag(ah + 512 + la8);
  bf16x8 al0 = ldfrag(al + la8), al1 = ldfrag(al + 512 + la8);

  float vrow[4];
  #pragma unroll
  for (int r = 0; r < 4; ++r) vrow[r] = vv[b * NN + n0 + q * 4 + r];

  f32x4 acc[FT];
  #pragma unroll
  for (int tt = 0; tt < FT; ++tt) {
    int c0 = cw + tt * 16;
    const unsigned short* bh = xhi + xb + c0 * 64;
    const unsigned short* bl = xlo + xb + c0 * 64;
    bf16x8 bh0 = ldfrag(bh + la8), bh1 = ldfrag(bh + 512 + la8);
    bf16x8 bl0 = ldfrag(bl + la8), bl1 = ldfrag(bl + 512 + la8);
    f32x4 bs = *(const f32x4*)&baset[(((size_t)(n0 >> 4) * 128 + (c0 >> 4)) * 64 + lane) * 4];
    f32x4 a = {0.f, 0.f, 0.f, 0.f};
    f32x4 bq = {0.f, 0.f, 0.f, 0.f};
    a = MFMA16(ah0, bh0, a, 0, 0, 0);
    a = MFMA16(ah1, bh1, a, 0, 0, 0);
    bq = MFMA16(ah0, bl0, bq, 0, 0, 0);
    bq = MFMA16(ah1, bl1, bq, 0, 0, 0);
    bq = MFMA16(al0, bh0, bq, 0, 0, 0);
    bq = MFMA16(al1, bh1, bq, 0, 0, 0);
    float vc = vv[b * NN + c0 + m];
    #pragma unroll
    for (int r = 0; r < 4; ++r)
      a[r] += bq[r] + bs[r] + vrow[r] - vc;
    acc[tt] = a;
  }

  // row max: per-lane over tiles, shuffle across 16 column-lanes, cross-wave LDS
  float mx[4];
  #pragma unroll
  for (int r = 0; r < 4; ++r) mx[r] = acc[0][r];
  #pragma unroll
  for (int tt = 1; tt < FT; ++tt)
    #pragma unroll
    for (int r = 0; r < 4; ++r) mx[r] = fmaxf(mx[r], acc[tt][r]);
  #pragma unroll
  for (int off = 8; off >= 1; off >>= 1)
    #pragma unroll
    for (int r = 0; r < 4; ++r) mx[r] = fmaxf(mx[r], __shfl_xor(mx[r], off, 64));
  if (m == 0) {
    #pragma unroll
    for (int r = 0; r < 4; ++r) redm[w][q * 4 + r] = mx[r];
  }
  __syncthreads();
  float mrow[4], sm[4];
  #pragma unroll
  for (int r = 0; r < 4; ++r) {
    int rr = q * 4 + r;
    float mv = redm[0][rr];
    #pragma unroll
    for (int ww = 1; ww < FW; ++ww) mv = fmaxf(mv, redm[ww][rr]);
    mrow[r] = mv;
    sm[r] = 0.f;
  }
  #pragma unroll
  for (int tt = 0; tt < FT; ++tt)
    #pragma unroll
    for (int r = 0; r < 4; ++r) {
      float e = __expf(acc[tt][r] - mrow[r]);
      acc[tt][r] = e;
      sm[r] += e;
    }
  #pragma unroll
  for (int off = 8; off >= 1; off >>= 1)
    #pragma unroll
    for (int r = 0; r < 4; ++r) sm[r] += __shfl_xor(sm[r], off, 64);
  if (m == 0) {
    #pragma unroll
    for (int r = 0; r < 4; ++r) reds[w][q * 4 + r] = sm[r];
  }
  __syncthreads();
  float inv[4];
  #pragma unroll
  for (int r = 0; r < 4; ++r) {
    int rr = q * 4 + r;
    float sv = reds[0][rr];
    #pragma unroll
    for (int ww = 1; ww < FW; ++ww) sv += reds[ww][rr];
    inv[r] = 1.f / sv;
  }
  #pragma unroll
  for (int tt = 0; tt < FT; ++tt) {
    int c = cw + tt * 16 + m;
    #pragma unroll
    for (int r = 0; r < 4; ++r)
      out[((size_t)b * NN + n0 + q * 4 + r) * NN + c] = acc[tt][r] * inv[r];
  }
}

// ---------------------------------------------------------------------------
// small-ws fallback (R1 VALU path, recomputes base dot per block)
// ---------------------------------------------------------------------------
__global__ __launch_bounds__(256) void fused_fallback(
    const float* __restrict__ x, const float* __restrict__ node1,
    const float* __restrict__ node2, const float* __restrict__ vv,
    float* __restrict__ out)
{
  __shared__ float xr[TM][DD];
  __shared__ float n1r[TM][DD];
  __shared__ float colbuf[2][DD / 2][MC + 1];
  __shared__ float redm[4][4];
  __shared__ float reds[4][4];

  int t = threadIdx.x;
  int b = blockIdx.y;
  int n0 = blockIdx.x * TM;
  int mloc = t & (MC - 1);
  int grp = t >> 7;
  int r0 = grp * 4;

  for (int i = t; i < TM * DD; i += 256) {
    xr[i >> 6][i & 63] = x[((size_t)b * NN + n0) * DD + i];
    n1r[i >> 6][i & 63] = node1[(size_t)n0 * DD + i];
  }
  float vrow[4];
  #pragma unroll
  for (int r = 0; r < 4; ++r) vrow[r] = vv[b * NN + n0 + r0 + r];

  float acc[4][NCH];

  #pragma unroll
  for (int c = 0; c < NCH; ++c) {
    float dacc[4] = {0.f, 0.f, 0.f, 0.f};
    float bacc[4] = {0.f, 0.f, 0.f, 0.f};
    #pragma unroll
    for (int h = 0; h < 2; ++h) {
      __syncthreads();
      #pragma unroll
      for (int i = 0; i < 8; ++i) {
        int f = i * 256 + t;
        int arr = f >> 10;
        int ff = f & 1023;
        int mm = ff >> 3, kq = ff & 7;
        const float* src = arr
            ? node2 + (size_t)(c * MC + mm) * DD + h * 32 + kq * 4
            : x + ((size_t)b * NN + c * MC + mm) * DD + h * 32 + kq * 4;
        float4 qv = *(const float4*)src;
        colbuf[arr][kq * 4 + 0][mm] = qv.x;
        colbuf[arr][kq * 4 + 1][mm] = qv.y;
        colbuf[arr][kq * 4 + 2][mm] = qv.z;
        colbuf[arr][kq * 4 + 3][mm] = qv.w;
      }
      __syncthreads();
      #pragma unroll
      for (int kb = 0; kb < 8; ++kb) {
        float ra[4][4], rb[4][4];
        #pragma unroll
        for (int r = 0; r < 4; ++r) {
          float4 qx = *(const float4*)&xr[r0 + r][h * 32 + kb * 4];
          ra[r][0] = qx.x; ra[r][1] = qx.y; ra[r][2] = qx.z; ra[r][3] = qx.w;
          float4 qn = *(const float4*)&n1r[r0 + r][h * 32 + kb * 4];
          rb[r][0] = qn.x; rb[r][1] = qn.y; rb[r][2] = qn.z; rb[r][3] = qn.w;
        }
        #pragma unroll
        for (int kk = 0; kk < 4; ++kk) {
          float cx = colbuf[0][kb * 4 + kk][mloc];
          float cn = colbuf[1][kb * 4 + kk][mloc];
          #pragma unroll
          for (int r = 0; r < 4; ++r) {
            dacc[r] += ra[r][kk] * cx;
            bacc[r] += rb[r][kk] * cn;
          }
        }
      }
    }
    float vc = vv[b * NN + c * MC + mloc];
    #pragma unroll
    for (int r = 0; r < 4; ++r)
      acc[r][c] = dacc[r] + vrow[r] - vc + fmaxf(bacc[r], 0.f);
  }

  float pm[4];
  #pragma unroll
  for (int r = 0; r < 4; ++r) {
    float mv = acc[r][0];
    #pragma unroll
    for (int c = 1; c < NCH; ++c) mv = fmaxf(mv, acc[r][c]);
    #pragma unroll
    for (int off = 32; off >= 1; off >>= 1)
      mv = fmaxf(mv, __shfl_xor(mv, off, 64));
    pm[r] = mv;
  }
  int w = t >> 6;
  if ((t & 63) == 0) {
    #pragma unroll
    for (int r = 0; r < 4; ++r) redm[w][r] = pm[r];
  }
  __syncthreads();
  float mrow[4], ps[4];
  #pragma unroll
  for (int r = 0; r < 4; ++r) {
    mrow[r] = fmaxf(redm[grp * 2][r], redm[grp * 2 + 1][r]);
    ps[r] = 0.f;
  }
  #pragma unroll
  for (int c = 0; c < NCH; ++c)
    #pragma unroll
    for (int r = 0; r < 4; ++r) {
      float e = __expf(acc[r][c] - mrow[r]);
      acc[r][c] = e;
      ps[r] += e;
    }
  #pragma unroll
  for (int r = 0; r < 4; ++r)
    #pragma unroll
    for (int off = 32; off >= 1; off >>= 1)
      ps[r] += __shfl_xor(ps[r], off, 64);
  if ((t & 63) == 0) {
    #pragma unroll
    for (int r = 0; r < 4; ++r) reds[w][r] = ps[r];
  }
  __syncthreads();
  float inv[4];
  #pragma unroll
  for (int r = 0; r < 4; ++r)
    inv[r] = 1.f / (reds[grp * 2][r] + reds[grp * 2 + 1][r]);
  #pragma unroll
  for (int c = 0; c < NCH; ++c)
    #pragma unroll
    for (int r = 0; r < 4; ++r)
      out[((size_t)b * NN + n0 + r0 + r) * NN + c * MC + mloc] = acc[r][c] * inv[r];
}

// ---------------------------------------------------------------------------
extern "C" void kernel_launch(void* const* d_in, const int* in_sizes, int n_in,
                              void* d_out, int out_size, void* d_ws, size_t ws_size,
                              hipStream_t stream)
{
  const float* x   = (const float*)d_in[0];
  const float* emb = (const float*)d_in[1];
  const float* w1w = (const float*)d_in[2];
  const float* w1b = (const float*)d_in[3];
  const float* w2w = (const float*)d_in[4];
  const float* w2b = (const float*)d_in[5];
  const float* wpw = (const float*)d_in[6];
  const float* wpb = (const float*)d_in[7];
  float* out = (float*)d_out;

  float* wsf   = (float*)d_ws;
  float* node1 = wsf;
  float* node2 = wsf + (size_t)NN * DD;
  float* v     = wsf + (size_t)2 * NN * DD;
  float* baset = wsf + (size_t)2 * NN * DD + (size_t)BB * NN;
  unsigned short* bfb = (unsigned short*)(baset + (size_t)NN * NN);
  unsigned short* xhi = bfb;
  unsigned short* xlo = xhi + (size_t)BB * NN * DD;
  unsigned short* n1hi = xlo + (size_t)BB * NN * DD;
  unsigned short* n1lo = n1hi + (size_t)NN * DD;
  unsigned short* n2hi = n1lo + (size_t)NN * DD;
  unsigned short* n2lo = n2hi + (size_t)NN * DD;

  size_t need_mfma = ((size_t)2 * NN * DD + (size_t)BB * NN + (size_t)NN * NN) * 4
                   + ((size_t)2 * BB * NN * DD + (size_t)4 * NN * DD) * 2;
  bool big = ws_size >= need_mfma;

  prep_all<<<2176, 256, 0, stream>>>(
      x, emb, w1w, w1b, w2w, w2b, wpw, wpb,
      node1, node2, n1hi, n1lo, n2hi, n2lo, xhi, xlo, v, big ? 1 : 0);

  if (big) {
    dim3 bgrid(NN / 16, 8);
    base_mfma<<<bgrid, 256, 0, stream>>>(n1hi, n1lo, n2hi, n2lo, baset);
    fused_mfma<<<NN / 16 * BB, 512, 0, stream>>>(xhi, xlo, baset, v, out);
  } else {
    dim3 grid(NN / TM, BB);
    fused_fallback<<<grid, 256, 0, stream>>>(x, node1, node2, v, out);
  }
}